// Round 2
// baseline (299.508 us; speedup 1.0000x reference)
//
#include <hip/hip_runtime.h>
#include <math.h>

#define HW      409600      // 640*640
#define HW4     102400      // HW/4 float4-groups per (batch,dim)
#define BATCH   8
#define NLAB    33
#define GX      128         // blocks per batch
#define NBLOCK  (GX*BATCH)  // 1024 total: 4 blocks/CU on 256 CUs -> co-resident
#define GPB     (HW4/GX)    // 800 float4-groups per block
#define NREP    8           // LDS bin replicas (per 8-lane cluster)
#define RS      201         // replica stride (198 fields, padded; 201%32=9 spreads banks)
// ws float layout per batch (stride WSB): sums[132] cnt_k[33]@132 cnt_i[33]@165 valsum@198
#define WSB     208
#define BAR_OFF (WSB*BATCH) // then 2 uint barrier counters

__global__ void init_ws(float* ws) {
    int i = blockIdx.x * 256 + threadIdx.x;
    if (i < BAR_OFF + 8) ws[i] = 0.f;
}

__device__ __forceinline__ void bar_arrive(unsigned* cnt) {
    __syncthreads();
    if (threadIdx.x == 0)
        __hip_atomic_fetch_add(cnt, 1u, __ATOMIC_RELEASE, __HIP_MEMORY_SCOPE_AGENT);
}
__device__ __forceinline__ void bar_wait(unsigned* cnt, unsigned n) {
    if (threadIdx.x == 0) {
        while (__hip_atomic_load(cnt, __ATOMIC_ACQUIRE, __HIP_MEMORY_SCOPE_AGENT) < n)
            __builtin_amdgcn_s_sleep(4);
    }
    __syncthreads();
}

__device__ __forceinline__ float wsload(const float* p) {
    return __hip_atomic_load(p, __ATOMIC_RELAXED, __HIP_MEMORY_SCOPE_AGENT);
}

__global__ __launch_bounds__(256, 4) void fused(const float* __restrict__ emb,
                                                const int*   __restrict__ inst,
                                                const float* __restrict__ kern,
                                                const float* __restrict__ tmask,
                                                float* ws, float* out) {
    __shared__ float    bins[NREP][RS];
    __shared__ unsigned labs[GPB];
    __shared__ float4   means4[NLAB];
    __shared__ float    invci[NLAB];
    __shared__ float    red[256];

    const int t   = threadIdx.x;
    const int bx  = blockIdx.x;
    const int b   = blockIdx.y;
    const int rep = (t >> 3) & (NREP - 1);
    unsigned* bar = (unsigned*)(ws + BAR_OFF);

    for (int i = t; i < NREP * RS; i += 256) (&bins[0][0])[i] = 0.f;
    __syncthreads();

    const size_t  base  = (size_t)b * HW;
    const float4* emb4  = (const float4*)(emb + base * 4);
    const int4*   inst4 = (const int4*)(inst + base);
    const float4* kern4 = (const float4*)(kern + base);
    const float4* tm4   = (const float4*)(tmask + base);
    const int     g0    = bx * GPB;
    float*        mb    = bins[rep];

    // ---------------- Phase A: segment sums/counts ----------------
    for (int lg = t; lg < GPB; lg += 256) {
        const int g = g0 + lg;
        int4   iv = inst4[g];
        float4 kv = kern4[g];
        float4 tv = tm4[g];
        int l0 = (tv.x > 0.5f) ? iv.x : 0;
        int l1 = (tv.y > 0.5f) ? iv.y : 0;
        int l2 = (tv.z > 0.5f) ? iv.z : 0;
        int l3 = (tv.w > 0.5f) ? iv.w : 0;
        labs[lg] = (unsigned)l0 | ((unsigned)l1 << 8) |
                   ((unsigned)l2 << 16) | ((unsigned)l3 << 24);
        if (l0) atomicAdd(&mb[l0 * 6 + 5], 1.f);
        if (l1) atomicAdd(&mb[l1 * 6 + 5], 1.f);
        if (l2) atomicAdd(&mb[l2 * 6 + 5], 1.f);
        if (l3) atomicAdd(&mb[l3 * 6 + 5], 1.f);
        bool k0 = l0 && (kv.x > 0.5f);
        bool k1 = l1 && (kv.y > 0.5f);
        bool k2 = l2 && (kv.z > 0.5f);
        bool k3 = l3 && (kv.w > 0.5f);
        if (k0 | k1 | k2 | k3) {
            float4 x0 = emb4[g];
            float4 x1 = emb4[g + HW4];
            float4 x2 = emb4[g + 2 * HW4];
            float4 x3 = emb4[g + 3 * HW4];
            if (k0) {
                float* bb = &mb[l0 * 6];
                atomicAdd(bb + 0, x0.x); atomicAdd(bb + 1, x1.x);
                atomicAdd(bb + 2, x2.x); atomicAdd(bb + 3, x3.x);
                atomicAdd(bb + 4, 1.f);
            }
            if (k1) {
                float* bb = &mb[l1 * 6];
                atomicAdd(bb + 0, x0.y); atomicAdd(bb + 1, x1.y);
                atomicAdd(bb + 2, x2.y); atomicAdd(bb + 3, x3.y);
                atomicAdd(bb + 4, 1.f);
            }
            if (k2) {
                float* bb = &mb[l2 * 6];
                atomicAdd(bb + 0, x0.z); atomicAdd(bb + 1, x1.z);
                atomicAdd(bb + 2, x2.z); atomicAdd(bb + 3, x3.z);
                atomicAdd(bb + 4, 1.f);
            }
            if (k3) {
                float* bb = &mb[l3 * 6];
                atomicAdd(bb + 0, x0.w); atomicAdd(bb + 1, x1.w);
                atomicAdd(bb + 2, x2.w); atomicAdd(bb + 3, x3.w);
                atomicAdd(bb + 4, 1.f);
            }
        }
    }
    __syncthreads();

    float* w = ws + b * WSB;
    for (int i = t; i < NLAB * 6; i += 256) {
        float v = 0.f;
        #pragma unroll
        for (int r = 0; r < NREP; ++r) v += bins[r][i];
        if (v != 0.f) {
            int lab = i / 6, f = i % 6;
            int dst = (f < 4) ? lab * 4 + f : ((f == 4) ? 132 + lab : 165 + lab);
            atomicAdd(w + dst, v);
        }
    }

    // ---------------- grid barrier 1 ----------------
    bar_arrive(&bar[0]);
    bar_wait(&bar[0], NBLOCK);

    // ---------------- Phase B: per-pixel val, register-accumulated ----------------
    if (t < NLAB) {
        float inv = 1.f / fmaxf(wsload(w + 132 + t), 1.f);
        float z = (t == 0) ? 0.f : 1.f;
        float4 m;
        m.x = z * wsload(w + t * 4 + 0) * inv;
        m.y = z * wsload(w + t * 4 + 1) * inv;
        m.z = z * wsload(w + t * 4 + 2) * inv;
        m.w = z * wsload(w + t * 4 + 3) * inv;
        means4[t] = m;
        invci[t]  = 1.f / fmaxf(wsload(w + 165 + t), 1.f);
    }
    __syncthreads();

    float acc = 0.f;
    for (int lg = t; lg < GPB; lg += 256) {
        unsigned pk = labs[lg];
        if (pk) {
            const int g = g0 + lg;
            float4 x0 = emb4[g];
            float4 x1 = emb4[g + HW4];
            float4 x2 = emb4[g + 2 * HW4];
            float4 x3 = emb4[g + 3 * HW4];
            #pragma unroll
            for (int e = 0; e < 4; ++e) {
                int l = (pk >> (8 * e)) & 255;
                if (l) {
                    float a0 = (e == 0) ? x0.x : (e == 1) ? x0.y : (e == 2) ? x0.z : x0.w;
                    float a1 = (e == 0) ? x1.x : (e == 1) ? x1.y : (e == 2) ? x1.z : x1.w;
                    float a2 = (e == 0) ? x2.x : (e == 1) ? x2.y : (e == 2) ? x2.z : x2.w;
                    float a3 = (e == 0) ? x3.x : (e == 1) ? x3.y : (e == 2) ? x3.z : x3.w;
                    float4 m = means4[l];
                    float d0 = a0 - m.x, d1 = a1 - m.y, d2 = a2 - m.z, d3 = a3 - m.w;
                    float dist = sqrtf(d0 * d0 + d1 * d1 + d2 * d2 + d3 * d3);
                    float u = fmaxf(dist - 0.5f, 0.f);
                    acc += __logf(u * u + 1.f) * invci[l];
                }
            }
        }
    }
    red[t] = acc;
    __syncthreads();
    for (int s = 128; s > 0; s >>= 1) {
        if (t < s) red[t] += red[t + s];
        __syncthreads();
    }
    if (t == 0) atomicAdd(w + 198, red[0]);

    // ---------------- grid barrier 2: arrive; only block (0,0) waits ----------------
    bar_arrive(&bar[1]);
    if (bx != 0 || b != 0) return;
    bar_wait(&bar[1], NBLOCK);

    // ---------------- Phase C: finalize scalar ----------------
    float total = 0.f;
    for (int bb = 0; bb < BATCH; ++bb) {
        const float* wb = ws + bb * WSB;
        __syncthreads();
        if (t < NLAB) {
            float inv = 1.f / fmaxf(wsload(wb + 132 + t), 1.f);
            float z = (t == 0) ? 0.f : 1.f;
            float4 m;
            m.x = z * wsload(wb + t * 4 + 0) * inv;
            m.y = z * wsload(wb + t * 4 + 1) * inv;
            m.z = z * wsload(wb + t * 4 + 2) * inv;
            m.w = z * wsload(wb + t * 4 + 3) * inv;
            means4[t] = m;
        }
        __syncthreads();
        float part = 0.f;
        if (t == 0) part = wsload(wb + 198) * (1.f / 32.f);   // l_agg
        float disp = 0.f;
        for (int p = t; p < 1024; p += 256) {
            int i = p >> 5, j = p & 31;
            if (i != j) {
                float4 mi = means4[i + 1], mj = means4[j + 1];
                float d0 = mi.x - mj.x, d1 = mi.y - mj.y;
                float d2 = mi.z - mj.z, d3 = mi.w - mj.w;
                float pd = sqrtf(d0 * d0 + d1 * d1 + d2 * d2 + d3 * d3);
                float u = fmaxf(3.0f - pd, 0.f);
                disp += __logf(u * u + 1.f);
            }
        }
        disp *= 1.f / 992.f;                                  // K*(K-1) = 32*31
        float regp = 0.f;
        if (t >= 1 && t < NLAB) {
            float4 m = means4[t];
            float n2 = m.x * m.x + m.y * m.y + m.z * m.z + m.w * m.w;
            regp = __logf(sqrtf(n2) + 1.f) * (0.001f / 33.f);
        }
        red[t] = part + disp + regp;
        __syncthreads();
        for (int s = 128; s > 0; s >>= 1) {
            if (t < s) red[t] += red[t + s];
            __syncthreads();
        }
        if (t == 0) total += red[0];
    }
    if (t == 0) out[0] = total * (1.f / BATCH);
}

extern "C" void kernel_launch(void* const* d_in, const int* in_sizes, int n_in,
                              void* d_out, int out_size, void* d_ws, size_t ws_size,
                              hipStream_t stream) {
    const float* emb   = (const float*)d_in[0];
    const int*   inst  = (const int*)  d_in[1];
    const float* kern  = (const float*)d_in[2];
    const float* tmask = (const float*)d_in[3];
    float* ws  = (float*)d_ws;
    float* out = (float*)d_out;

    init_ws<<<dim3((BAR_OFF + 8 + 255) / 256), 256, 0, stream>>>(ws);
    fused<<<dim3(GX, BATCH), 256, 0, stream>>>(emb, inst, kern, tmask, ws, out);
}

// Round 3
// 173.287 us; speedup vs baseline: 1.7284x; 1.7284x over previous
//
#include <hip/hip_runtime.h>
#include <math.h>

#define HW    409600      // 640*640
#define HW4   102400      // float4-groups per (batch,dim)
#define BATCH 8
#define NLAB  33
#define GXB   200         // blocks per batch; 512 groups/block (2 per thread)
#define NREP  8           // LDS bin replicas (per 8-lane cluster)
#define RS    201         // replica stride, 201%32=9 spreads banks
// ws float layout per batch (stride WSB): sums[132] cnt_k[33]@132 cnt_i[33]@165 valsum@198
#define WSB   208
#define LAB_OFF 8192      // byte offset of packed label array in ws
#define LAB_BYTES (4u * HW4 * BATCH)   // 3,276,800

__global__ void init_ws(float* ws) {
    int i = blockIdx.x * 256 + threadIdx.x;
    if (i < WSB * BATCH) ws[i] = 0.f;
}

__device__ __forceinline__ float getc(const float4& v, int e) {
    return (e == 0) ? v.x : (e == 1) ? v.y : (e == 2) ? v.z : v.w;
}
__device__ __forceinline__ int geti(const int4& v, int e) {
    return (e == 0) ? v.x : (e == 1) ? v.y : (e == 2) ? v.z : v.w;
}

__device__ __forceinline__ void acc1(int l, bool k,
                                     float x0, float x1, float x2, float x3,
                                     float* mb) {
    if (l) {
        float* bb = mb + l * 6;
        atomicAdd(bb + 5, 1.f);          // cnt_i
        if (k) {
            atomicAdd(bb + 0, x0);
            atomicAdd(bb + 1, x1);
            atomicAdd(bb + 2, x2);
            atomicAdd(bb + 3, x3);
            atomicAdd(bb + 4, 1.f);      // cnt_k
        }
    }
}

__global__ __launch_bounds__(256, 4) void pass1(const float* __restrict__ emb,
                                                const int*   __restrict__ inst,
                                                const float* __restrict__ kern,
                                                const float* __restrict__ tmask,
                                                float*       __restrict__ ws,
                                                unsigned*    __restrict__ labs) {
    __shared__ float bins[NREP][RS];
    const int t = threadIdx.x, bx = blockIdx.x, b = blockIdx.y;
    float* mb = bins[(t >> 3) & (NREP - 1)];
    for (int i = t; i < NREP * RS; i += 256) (&bins[0][0])[i] = 0.f;
    __syncthreads();

    const size_t  base  = (size_t)b * HW;
    const float4* emb4  = (const float4*)(emb + base * 4);
    const int4*   inst4 = (const int4*)(inst + base);
    const float4* kern4 = (const float4*)(kern + base);
    const float4* tm4   = (const float4*)(tmask + base);
    const int gA = bx * 512 + t, gB = gA + 256;

    // issue all 14 loads up front (ILP: keep them in flight)
    int4   ivA = inst4[gA];          int4   ivB = inst4[gB];
    float4 tvA = tm4[gA];            float4 tvB = tm4[gB];
    float4 kvA = kern4[gA];          float4 kvB = kern4[gB];
    float4 x0A = emb4[gA];           float4 x0B = emb4[gB];
    float4 x1A = emb4[gA + HW4];     float4 x1B = emb4[gB + HW4];
    float4 x2A = emb4[gA + 2*HW4];   float4 x2B = emb4[gB + 2*HW4];
    float4 x3A = emb4[gA + 3*HW4];   float4 x3B = emb4[gB + 3*HW4];

    int lA0 = (tvA.x > 0.5f) ? ivA.x : 0;
    int lA1 = (tvA.y > 0.5f) ? ivA.y : 0;
    int lA2 = (tvA.z > 0.5f) ? ivA.z : 0;
    int lA3 = (tvA.w > 0.5f) ? ivA.w : 0;
    int lB0 = (tvB.x > 0.5f) ? ivB.x : 0;
    int lB1 = (tvB.y > 0.5f) ? ivB.y : 0;
    int lB2 = (tvB.z > 0.5f) ? ivB.z : 0;
    int lB3 = (tvB.w > 0.5f) ? ivB.w : 0;

    if (labs) {
        labs[(size_t)b * HW4 + gA] = (unsigned)lA0 | ((unsigned)lA1 << 8) |
                                     ((unsigned)lA2 << 16) | ((unsigned)lA3 << 24);
        labs[(size_t)b * HW4 + gB] = (unsigned)lB0 | ((unsigned)lB1 << 8) |
                                     ((unsigned)lB2 << 16) | ((unsigned)lB3 << 24);
    }

    acc1(lA0, kvA.x > 0.5f, x0A.x, x1A.x, x2A.x, x3A.x, mb);
    acc1(lA1, kvA.y > 0.5f, x0A.y, x1A.y, x2A.y, x3A.y, mb);
    acc1(lA2, kvA.z > 0.5f, x0A.z, x1A.z, x2A.z, x3A.z, mb);
    acc1(lA3, kvA.w > 0.5f, x0A.w, x1A.w, x2A.w, x3A.w, mb);
    acc1(lB0, kvB.x > 0.5f, x0B.x, x1B.x, x2B.x, x3B.x, mb);
    acc1(lB1, kvB.y > 0.5f, x0B.y, x1B.y, x2B.y, x3B.y, mb);
    acc1(lB2, kvB.z > 0.5f, x0B.z, x1B.z, x2B.z, x3B.z, mb);
    acc1(lB3, kvB.w > 0.5f, x0B.w, x1B.w, x2B.w, x3B.w, mb);
    __syncthreads();

    float* w = ws + b * WSB;
    for (int i = t; i < NLAB * 6; i += 256) {
        float v = 0.f;
        #pragma unroll
        for (int r = 0; r < NREP; ++r) v += bins[r][i];
        if (v != 0.f) {
            int lab = i / 6, f = i % 6;
            int dst = (f < 4) ? lab * 4 + f : ((f == 4) ? 132 + lab : 165 + lab);
            atomicAdd(w + dst, v);
        }
    }
}

template<bool USE_LABS>
__global__ __launch_bounds__(256, 4) void pass2(const float* __restrict__ emb,
                                                const int*   __restrict__ inst,
                                                const float* __restrict__ tmask,
                                                float*       __restrict__ ws,
                                                const unsigned* __restrict__ labs) {
    __shared__ float4 means4[NLAB];
    __shared__ float  invci[NLAB];
    __shared__ float  red[256];
    const int t = threadIdx.x, bx = blockIdx.x, b = blockIdx.y;
    float* w = ws + b * WSB;

    if (t < NLAB) {
        float inv = 1.f / fmaxf(w[132 + t], 1.f);
        float z = (t == 0) ? 0.f : 1.f;
        means4[t] = make_float4(z * w[t * 4 + 0] * inv, z * w[t * 4 + 1] * inv,
                                z * w[t * 4 + 2] * inv, z * w[t * 4 + 3] * inv);
        invci[t] = 1.f / fmaxf(w[165 + t], 1.f);
    }
    __syncthreads();

    const size_t  base = (size_t)b * HW;
    const float4* emb4 = (const float4*)(emb + base * 4);
    const int gA = bx * 512 + t, gB = gA + 256;

    unsigned pkA, pkB;
    if (USE_LABS) {
        pkA = labs[(size_t)b * HW4 + gA];
        pkB = labs[(size_t)b * HW4 + gB];
    } else {
        const int4*   inst4 = (const int4*)(inst + base);
        const float4* tm4   = (const float4*)(tmask + base);
        int4 ivA = inst4[gA], ivB = inst4[gB];
        float4 tvA = tm4[gA], tvB = tm4[gB];
        pkA = (unsigned)((tvA.x > 0.5f) ? ivA.x : 0)        |
              ((unsigned)((tvA.y > 0.5f) ? ivA.y : 0) << 8) |
              ((unsigned)((tvA.z > 0.5f) ? ivA.z : 0) << 16)|
              ((unsigned)((tvA.w > 0.5f) ? ivA.w : 0) << 24);
        pkB = (unsigned)((tvB.x > 0.5f) ? ivB.x : 0)        |
              ((unsigned)((tvB.y > 0.5f) ? ivB.y : 0) << 8) |
              ((unsigned)((tvB.z > 0.5f) ? ivB.z : 0) << 16)|
              ((unsigned)((tvB.w > 0.5f) ? ivB.w : 0) << 24);
    }

    // issue all 8 emb loads up front
    float4 x0A = emb4[gA];           float4 x0B = emb4[gB];
    float4 x1A = emb4[gA + HW4];     float4 x1B = emb4[gB + HW4];
    float4 x2A = emb4[gA + 2*HW4];   float4 x2B = emb4[gB + 2*HW4];
    float4 x3A = emb4[gA + 3*HW4];   float4 x3B = emb4[gB + 3*HW4];

    float acc = 0.f;
    #pragma unroll
    for (int e = 0; e < 4; ++e) {
        int l = (pkA >> (8 * e)) & 255;
        if (l) {
            float4 m = means4[l];
            float d0 = getc(x0A, e) - m.x, d1 = getc(x1A, e) - m.y;
            float d2 = getc(x2A, e) - m.z, d3 = getc(x3A, e) - m.w;
            float dist = sqrtf(d0 * d0 + d1 * d1 + d2 * d2 + d3 * d3);
            float u = fmaxf(dist - 0.5f, 0.f);
            acc += __logf(u * u + 1.f) * invci[l];
        }
    }
    #pragma unroll
    for (int e = 0; e < 4; ++e) {
        int l = (pkB >> (8 * e)) & 255;
        if (l) {
            float4 m = means4[l];
            float d0 = getc(x0B, e) - m.x, d1 = getc(x1B, e) - m.y;
            float d2 = getc(x2B, e) - m.z, d3 = getc(x3B, e) - m.w;
            float dist = sqrtf(d0 * d0 + d1 * d1 + d2 * d2 + d3 * d3);
            float u = fmaxf(dist - 0.5f, 0.f);
            acc += __logf(u * u + 1.f) * invci[l];
        }
    }

    red[t] = acc;
    __syncthreads();
    for (int s = 128; s > 0; s >>= 1) {
        if (t < s) red[t] += red[t + s];
        __syncthreads();
    }
    if (t == 0) atomicAdd(w + 198, red[0]);
}

__global__ __launch_bounds__(256) void final_kernel(const float* __restrict__ ws,
                                                    float* __restrict__ out) {
    __shared__ float4 means4[NLAB];
    __shared__ float  red[256];
    int t = threadIdx.x;
    float total = 0.f;
    for (int b = 0; b < BATCH; ++b) {
        const float* w = ws + b * WSB;
        __syncthreads();
        if (t < NLAB) {
            float inv = 1.f / fmaxf(w[132 + t], 1.f);
            float z = (t == 0) ? 0.f : 1.f;
            means4[t] = make_float4(z * w[t * 4 + 0] * inv, z * w[t * 4 + 1] * inv,
                                    z * w[t * 4 + 2] * inv, z * w[t * 4 + 3] * inv);
        }
        __syncthreads();
        float part = 0.f;
        if (t == 0) part = w[198] * (1.f / 32.f);             // l_agg
        float disp = 0.f;
        for (int p = t; p < 1024; p += 256) {
            int i = p >> 5, j = p & 31;
            if (i != j) {
                float4 mi = means4[i + 1], mj = means4[j + 1];
                float d0 = mi.x - mj.x, d1 = mi.y - mj.y;
                float d2 = mi.z - mj.z, d3 = mi.w - mj.w;
                float pd = sqrtf(d0 * d0 + d1 * d1 + d2 * d2 + d3 * d3);
                float u = fmaxf(3.0f - pd, 0.f);
                disp += __logf(u * u + 1.f);
            }
        }
        disp *= 1.f / 992.f;                                  // 32*31
        float regp = 0.f;
        if (t >= 1 && t < NLAB) {
            float4 m = means4[t];
            float n2 = m.x * m.x + m.y * m.y + m.z * m.z + m.w * m.w;
            regp = __logf(sqrtf(n2) + 1.f) * (0.001f / 33.f);
        }
        red[t] = part + disp + regp;
        __syncthreads();
        for (int s = 128; s > 0; s >>= 1) {
            if (t < s) red[t] += red[t + s];
            __syncthreads();
        }
        if (t == 0) total += red[0];
    }
    if (t == 0) out[0] = total * (1.f / BATCH);
}

extern "C" void kernel_launch(void* const* d_in, const int* in_sizes, int n_in,
                              void* d_out, int out_size, void* d_ws, size_t ws_size,
                              hipStream_t stream) {
    const float* emb   = (const float*)d_in[0];
    const int*   inst  = (const int*)  d_in[1];
    const float* kern  = (const float*)d_in[2];
    const float* tmask = (const float*)d_in[3];
    float* ws  = (float*)d_ws;
    float* out = (float*)d_out;

    const bool use_labs = ws_size >= (size_t)LAB_OFF + LAB_BYTES;
    unsigned* labs = use_labs ? (unsigned*)((char*)d_ws + LAB_OFF) : nullptr;

    init_ws<<<dim3((WSB * BATCH + 255) / 256), 256, 0, stream>>>(ws);
    dim3 grid(GXB, BATCH);
    pass1<<<grid, 256, 0, stream>>>(emb, inst, kern, tmask, ws, labs);
    if (use_labs) pass2<true ><<<grid, 256, 0, stream>>>(emb, inst, tmask, ws, labs);
    else          pass2<false><<<grid, 256, 0, stream>>>(emb, inst, tmask, ws, nullptr);
    final_kernel<<<1, 256, 0, stream>>>(ws, out);
}